// Round 6
// baseline (186.472 us; speedup 1.0000x reference)
//
#include <hip/hip_runtime.h>

// QRNN: SEQ=4096, BATCH=8, CIN=256, HID=256, K=2 (lookback=1)
// R6: barrier-free GEMM — MFMA fragments loaded DIRECTLY global->VGPR
//     (bf16x8 dwordx4 per fragment), register double-buffered K-loop,
//     no LDS staging (B is L2-resident 0.5MB; A is L3-hot). LDS used only
//     for the epilogue transpose. Scans identical to R5 (act fused there).
//
// ws: zbf 16MB | fbf 16MB | Xbf 16MB (dead after gemm; Ac/Cc/Hs aliased) | Bm 0.5MB

#define SEQn 4096
#define NCH 2048          // BATCH*HID channels
#define CHUNK 32
#define NCHUNK 128

typedef __attribute__((ext_vector_type(8))) short bf16x8;
typedef __attribute__((ext_vector_type(4))) float floatx4;

__device__ __forceinline__ unsigned short f2bf(float x) {
  unsigned int u = __float_as_uint(x);
  u += 0x7fffu + ((u >> 16) & 1u);     // RNE
  return (unsigned short)(u >> 16);
}
__device__ __forceinline__ float bf2f(ushort u) {
  return __uint_as_float((unsigned int)u << 16);
}
__device__ __forceinline__ float sigf(float x) {
  return __builtin_amdgcn_rcpf(1.0f + __expf(-x));
}
__device__ __forceinline__ float qgelu(float x) {
  return x * sigf(1.702f * x);
}

// ---- 1) merged pack: blocks [0,1024) pack W, rest pack X ----
__global__ void pack_kernel(const float* __restrict__ X,
                            const float* __restrict__ Wz, const float* __restrict__ Wf,
                            ushort* __restrict__ Xbf, ushort* __restrict__ Bm) {
  if (blockIdx.x < 1024) {
    int idx = blockIdx.x * 256 + threadIdx.x;        // 0..262143
    int n = idx >> 9, kin = idx & 511;
    const float* W = (n < 256) ? Wz : Wf;
    int h = n & 255, c = kin & 255, tap = kin >> 8;  // kin<256: tap0 (X[s-1])
    Bm[idx] = f2bf(W[h * 512 + c * 2 + tap]);
  } else {
    int idx = (blockIdx.x - 1024) * 256 + threadIdx.x;
    const int total4 = ((SEQn + 1) * NCH) / 4;       // 2,097,664
    if (idx >= total4) return;
    const int pad4 = NCH / 4;
    float4 v;
    if (idx < pad4) { v.x = 0.f; v.y = 0.f; v.z = 0.f; v.w = 0.f; }
    else v = ((const float4*)X)[idx - pad4];
    ushort4 o;
    o.x = f2bf(v.x); o.y = f2bf(v.y); o.z = f2bf(v.z); o.w = f2bf(v.w);
    ((ushort4*)Xbf)[idx] = o;
  }
}

// ---- 2) GEMM 128x128/block, 64x64/wave, direct-from-global fragments ----
// A[m][kin]: kin<256 -> Xbf[m*256+kin] (tap0 = X[s-1]); kin>=256 -> +1792 (tap1)
// B[n][kin]: Bm[n*512+kin]
__global__ __launch_bounds__(256) void gemm_kernel(
    const ushort* __restrict__ Xbf, const ushort* __restrict__ Bm,
    ushort* __restrict__ zout, ushort* __restrict__ fout) {
  __shared__ __align__(16) ushort sT[64 * 136];   // epilogue transpose only

  const int tid  = threadIdx.x;
  const int wave = tid >> 6;
  const int lane = tid & 63;
  const int quad = lane >> 4;
  const int lrow = lane & 15;
  const int wm = wave >> 1;          // 2x2 wave grid, 64x64 each
  const int wn = wave & 1;
  const int bm = blockIdx.x;         // 0..255
  const int bn = blockIdx.y;         // 0..3 (0,1=Z; 2,3=F)

  // per-lane fragment base pointers (A-operand layout: lane reads
  // A[m = tile+fi*16+lrow][k = kstep*32 + quad*8 .. +8])
  const ushort* Abase = Xbf + (size_t)(bm * 128 + wm * 64 + lrow) * 256;
  const ushort* Bbase = Bm  + (size_t)(bn * 128 + wn * 64 + lrow) * 512;

  floatx4 acc[4][4];
#pragma unroll
  for (int i = 0; i < 4; ++i)
#pragma unroll
    for (int j = 0; j < 4; ++j)
      acc[i][j] = (floatx4){0.f, 0.f, 0.f, 0.f};

  bf16x8 a[2][4], b[2][4];
  // prefetch k-step 0
  {
    const int kk = quad * 8;                        // < 256: tap0 region
#pragma unroll
    for (int fi = 0; fi < 4; ++fi)
      a[0][fi] = *(const bf16x8*)(Abase + fi * 4096 + kk);
#pragma unroll
    for (int fj = 0; fj < 4; ++fj)
      b[0][fj] = *(const bf16x8*)(Bbase + fj * 8192 + kk);
  }

#pragma unroll
  for (int k = 0; k < 16; ++k) {                    // K=512 in steps of 32
    const int cur = k & 1, nxt = cur ^ 1;
    if (k < 15) {
      const int kk = (k + 1) * 32 + quad * 8;
      const int cA = (kk < 256) ? kk : kk + 1792;   // tap1 lives +2048-256
#pragma unroll
      for (int fi = 0; fi < 4; ++fi)
        a[nxt][fi] = *(const bf16x8*)(Abase + fi * 4096 + cA);
#pragma unroll
      for (int fj = 0; fj < 4; ++fj)
        b[nxt][fj] = *(const bf16x8*)(Bbase + fj * 8192 + kk);
    }
#pragma unroll
    for (int fi = 0; fi < 4; ++fi)
#pragma unroll
      for (int fj = 0; fj < 4; ++fj)
        acc[fi][fj] = __builtin_amdgcn_mfma_f32_16x16x32_bf16(a[cur][fi], b[cur][fj], acc[fi][fj], 0, 0, 0);
  }

  // epilogue (raw): f2bf -> sT (64 x 136 padded) -> coalesced dwordx4
  const bool isZ = (bn < 2);
  ushort* gout = isZ ? zout : fout;
  const int ncol0 = (bn & 1) * 128;

  for (int round = 0; round < 2; ++round) {
    __syncthreads();
    if (wm == round) {
#pragma unroll
      for (int fi = 0; fi < 4; ++fi)
#pragma unroll
        for (int fj = 0; fj < 4; ++fj)
#pragma unroll
          for (int r = 0; r < 4; ++r)
            sT[(fi * 16 + quad * 4 + r) * 136 + wn * 64 + fj * 16 + lrow] = f2bf(acc[fi][fj][r]);
    }
    __syncthreads();
#pragma unroll
    for (int it = 0; it < 4; ++it) {
      int e = tid + it * 256;           // 1024 segs = 64 rows x 16 segs
      int row = e >> 4, seg = e & 15;
      uint4 v = *(uint4*)&sT[row * 136 + seg * 8];
      *(uint4*)(gout + (size_t)(bm * 128 + round * 64 + row) * 256 + ncol0 + seg * 8) = v;
    }
  }
}

// ---- 3) per-chunk reduction, 2 channels/thread, fused bias+activation ----
__global__ void scanA_kernel(const ushort* __restrict__ z, const ushort* __restrict__ f,
                             const float* __restrict__ bz, const float* __restrict__ bfb,
                             float* __restrict__ Ac, float* __restrict__ Cc) {
  int t = blockIdx.x * blockDim.x + threadIdx.x;   // 0..131071
  int ch2 = t & 1023;
  int j = t >> 10;                                  // 0..127
  const int h0 = (2 * ch2) & 255, h1 = h0 + 1;
  const float zb0 = bz[h0], zb1 = bz[h1];
  const float fb0 = bfb[h0], fb1 = bfb[h1];
  const size_t base = (size_t)j * CHUNK * NCH + 2 * ch2;
  const ushort* zp = z + base;
  const ushort* fp = f + base;
  float A0 = 1.0f, C0 = 0.0f, A1 = 1.0f, C1 = 0.0f;
#pragma unroll
  for (int i = 0; i < CHUNK; ++i) {
    ushort2 fv = *(const ushort2*)(fp + (size_t)i * NCH);
    ushort2 zv = *(const ushort2*)(zp + (size_t)i * NCH);
    float f0 = sigf(bf2f(fv.x) + fb0), f1 = sigf(bf2f(fv.y) + fb1);
    float z0 = qgelu(bf2f(zv.x) + zb0), z1 = qgelu(bf2f(zv.y) + zb1);
    float a0 = 1.0f - f0, a1 = 1.0f - f1;
    C0 = fmaf(a0, C0, f0 * z0); A0 *= a0;
    C1 = fmaf(a1, C1, f1 * z1); A1 *= a1;
  }
  float2 Av = {A0, A1}, Cv = {C0, C1};
  *(float2*)(Ac + (size_t)j * NCH + 2 * ch2) = Av;
  *(float2*)(Cc + (size_t)j * NCH + 2 * ch2) = Cv;
}

// ---- 4) cross-chunk scan: one wave per channel, shfl Hillis-Steele ----
__global__ void scanB_kernel(const float* __restrict__ hidden,
                             const float* __restrict__ Ac, const float* __restrict__ Cc,
                             float* __restrict__ Hs) {
  const int lane = threadIdx.x & 63;
  const int ch = blockIdx.x * 4 + (threadIdx.x >> 6);   // 512 blocks x 4 waves
  const int j0 = 2 * lane, j1 = 2 * lane + 1;
  float a0 = Ac[j0 * NCH + ch], c0 = Cc[j0 * NCH + ch];
  float a1 = Ac[j1 * NCH + ch], c1 = Cc[j1 * NCH + ch];
  float a = a0 * a1;
  float c = fmaf(a1, c0, c1);
#pragma unroll
  for (int d = 1; d < 64; d <<= 1) {
    float pa = __shfl_up(a, d, 64);
    float pc = __shfl_up(c, d, 64);
    if (lane >= d) { c = fmaf(a, pc, c); a *= pa; }
  }
  float xa = __shfl_up(a, 1, 64), xc = __shfl_up(c, 1, 64);
  if (lane == 0) { xa = 1.0f; xc = 0.0f; }
  float h0 = hidden[ch];
  float hs0 = fmaf(xa, h0, xc);
  Hs[j0 * NCH + ch] = hs0;
  Hs[j1 * NCH + ch] = fmaf(a0, hs0, c0);
}

// ---- 5) replay within chunk, 2 channels/thread, fused bias+activation ----
__global__ void scanC_kernel(const ushort* __restrict__ z, const ushort* __restrict__ f,
                             const float* __restrict__ bz, const float* __restrict__ bfb,
                             const float* __restrict__ Hs, float* __restrict__ out) {
  int t = blockIdx.x * blockDim.x + threadIdx.x;   // 0..131071
  int ch2 = t & 1023;
  int j = t >> 10;
  const int h0i = (2 * ch2) & 255, h1i = h0i + 1;
  const float zb0 = bz[h0i], zb1 = bz[h1i];
  const float fb0 = bfb[h0i], fb1 = bfb[h1i];
  float2 hv = *(const float2*)(Hs + (size_t)j * NCH + 2 * ch2);
  float h0 = hv.x, h1 = hv.y;
  const size_t base = (size_t)j * CHUNK * NCH + 2 * ch2;
  const ushort* zp = z + base;
  const ushort* fp = f + base;
  float* op = out + base;
#pragma unroll
  for (int i = 0; i < CHUNK; ++i) {
    ushort2 fv = *(const ushort2*)(fp + (size_t)i * NCH);
    ushort2 zv = *(const ushort2*)(zp + (size_t)i * NCH);
    float f0 = sigf(bf2f(fv.x) + fb0), f1 = sigf(bf2f(fv.y) + fb1);
    float z0 = qgelu(bf2f(zv.x) + zb0), z1 = qgelu(bf2f(zv.y) + zb1);
    h0 = fmaf(f0, z0 - h0, h0);
    h1 = fmaf(f1, z1 - h1, h1);
    float2 o = {h0, h1};
    *(float2*)(op + (size_t)i * NCH) = o;
  }
  if (j == NCHUNK - 1) {
    float2 o = {h0, h1};
    *(float2*)(out + (size_t)SEQn * NCH + 2 * ch2) = o;   // h_last row
  }
}

extern "C" void kernel_launch(void* const* d_in, const int* in_sizes, int n_in,
                              void* d_out, int out_size, void* d_ws, size_t ws_size,
                              hipStream_t stream) {
  const float* X      = (const float*)d_in[0];
  const float* hidden = (const float*)d_in[1];
  const float* Wz     = (const float*)d_in[2];
  const float* bz     = (const float*)d_in[3];
  const float* Wf     = (const float*)d_in[4];
  const float* bfb    = (const float*)d_in[5];
  float* out = (float*)d_out;

  char* ws = (char*)d_ws;
  ushort* zbf = (ushort*)ws;                       // 16,777,216 B
  ushort* fbf = (ushort*)(ws + 16777216);          // 16,777,216 B
  ushort* Xbf = (ushort*)(ws + 33554432);          // 16,781,312 B (dead after gemm)
  ushort* Bm  = (ushort*)(ws + 50335744);          //    524,288 B
  // aliased over Xbf (used only after gemm completes):
  float* Ac = (float*)(ws + 33554432);
  float* Cc = (float*)(ws + 34603008);
  float* Hs = (float*)(ws + 35651584);

  pack_kernel<<<9218, 256, 0, stream>>>(X, Wz, Wf, Xbf, Bm);
  dim3 ggrid(256, 4);
  gemm_kernel<<<ggrid, 256, 0, stream>>>(Xbf, Bm, zbf, fbf);
  scanA_kernel<<<512, 256, 0, stream>>>(zbf, fbf, bz, bfb, Ac, Cc);
  scanB_kernel<<<512, 256, 0, stream>>>(hidden, Ac, Cc, Hs);
  scanC_kernel<<<512, 256, 0, stream>>>(zbf, fbf, bz, bfb, Hs, out);
}

// Round 7
// 158.837 us; speedup vs baseline: 1.1740x; 1.1740x over previous
//
#include <hip/hip_runtime.h>

// QRNN: SEQ=4096, BATCH=8, CIN=256, HID=256, K=2 (lookback=1)
// R7: R3 structure (best measured), pack_x ELIMINATED — GEMM stages A directly
//     from fp32 X with in-register cvt (tap0 row = m-8, tap1 row = m; zero if m<8).
//     B staged via global_load_lds. XOR-swizzled LDS, BK=64, act in epilogue.
//
// ws: zbf 16MB | fbf 16MB | Ac/Cc/Hs 3MB | Bm 0.5MB  (~36 MB)

#define SEQn 4096
#define NCH 2048          // BATCH*HID channels
#define CHUNK 32
#define NCHUNK 128

typedef __attribute__((ext_vector_type(8))) short bf16x8;
typedef __attribute__((ext_vector_type(4))) float floatx4;

__device__ __forceinline__ unsigned short f2bf(float x) {
  unsigned int u = __float_as_uint(x);
  u += 0x7fffu + ((u >> 16) & 1u);     // RNE
  return (unsigned short)(u >> 16);
}
__device__ __forceinline__ float bf2f(ushort u) {
  return __uint_as_float((unsigned int)u << 16);
}
__device__ __forceinline__ float sigf(float x) {
  return __builtin_amdgcn_rcpf(1.0f + __expf(-x));
}

// ---- 1) pack W only: Bm[n*512+kin] bf16 (n<256:Z else F; kin<256: tap0) ----
__global__ void pack_kernel(const float* __restrict__ Wz, const float* __restrict__ Wf,
                            ushort* __restrict__ Bm) {
  int idx = blockIdx.x * 256 + threadIdx.x;        // 0..262143
  int n = idx >> 9, kin = idx & 511;
  const float* W = (n < 256) ? Wz : Wf;
  int h = n & 255, c = kin & 255, tap = kin >> 8;  // kin<256: tap0 (X[s-1])
  Bm[idx] = f2bf(W[h * 512 + c * 2 + tap]);
}

// ---- 2) GEMM 128x128, BK=64, swizzled LDS; A from fp32 X (in-kernel cvt) ----
// A[m][kin]: kin<256 -> X[(m-8)*256+kin] (0 if m<8); kin>=256 -> X[m*256+kin-256]
__global__ __launch_bounds__(256) void gemm_kernel(
    const float* __restrict__ X, const ushort* __restrict__ Bm,
    const float* __restrict__ bz, const float* __restrict__ bfb,
    ushort* __restrict__ zout, ushort* __restrict__ fout) {
  __shared__ __align__(16) char smem_raw[32768];
  ushort* sA = (ushort*)smem_raw;                 // 128 rows x 64 k
  ushort* sB = (ushort*)(smem_raw + 16384);       // 128 cols x 64 k
  ushort* sT = (ushort*)smem_raw;                 // epilogue 64 x 136

  const int tid  = threadIdx.x;
  const int wave = tid >> 6;
  const int lane = tid & 63;
  const int quad = lane >> 4;
  const int lrow = lane & 15;
  const int wm = wave >> 1;          // 2x2 wave grid, 64x64 each
  const int wn = wave & 1;
  const int bm = blockIdx.x;         // 0..255
  const int bn = blockIdx.y;         // 0..3 (0,1=Z; 2,3=F)

  floatx4 acc[4][4];
#pragma unroll
  for (int i = 0; i < 4; ++i)
#pragma unroll
    for (int j = 0; j < 4; ++j)
      acc[i][j] = (floatx4){0.f, 0.f, 0.f, 0.f};

  // staging coords: 4 segs each for A and B per thread
  // LDS slot (r, s) holds global k-seg s^(r&7); seg = 8 bf16 = 16 B
  int rowS[4], gko[4];
#pragma unroll
  for (int it = 0; it < 4; ++it) {
    int g = wave * 256 + it * 64 + lane;     // LDS seg index 0..1023
    int row = g >> 3, ks8 = g & 7;
    rowS[it] = row;
    gko[it] = (ks8 ^ (row & 7)) * 8;         // swizzled global k offset
  }
  char* ldsB = (char*)sB + wave * 4096 + (lane << 4);

  for (int k0 = 0; k0 < 512; k0 += 64) {
    // A: load fp32, cvt, ds_write (same swizzle as B)
    float4 alo[4], ahi[4];
#pragma unroll
    for (int it = 0; it < 4; ++it) {
      const int kk = k0 + gko[it];
      const int m = bm * 128 + rowS[it];
      const float* src = (kk < 256) ? (X + (size_t)(m - 8) * 256 + kk)
                                    : (X + (size_t)m * 256 + (kk - 256));
      const bool valid = (kk >= 256) || (m >= 8);
      if (valid) {
        alo[it] = *(const float4*)src;
        ahi[it] = *(const float4*)(src + 4);
      } else {
        alo[it] = (float4){0.f, 0.f, 0.f, 0.f};
        ahi[it] = (float4){0.f, 0.f, 0.f, 0.f};
      }
    }
    __syncthreads();                 // prev iter ds_reads done
#pragma unroll
    for (int it = 0; it < 4; ++it) {
      const int kk = k0 + gko[it];
      __builtin_amdgcn_global_load_lds(
          (const __attribute__((address_space(1))) void*)(Bm + (size_t)(bn * 128 + rowS[it]) * 512 + kk),
          (__attribute__((address_space(3))) void*)(ldsB + it * 1024), 16, 0, 0);
      ushort4 lo4 = {f2bf(alo[it].x), f2bf(alo[it].y), f2bf(alo[it].z), f2bf(alo[it].w)};
      ushort4 hi4 = {f2bf(ahi[it].x), f2bf(ahi[it].y), f2bf(ahi[it].z), f2bf(ahi[it].w)};
      ushort* dst = sA + (size_t)(wave * 256 + it * 64 + lane) * 8;
      *(ushort4*)dst = lo4;
      *(ushort4*)(dst + 4) = hi4;
    }
    __syncthreads();

    bf16x8 af[4][2], bfr[4][2];
#pragma unroll
    for (int fi = 0; fi < 4; ++fi) {
      const int r = wm * 64 + fi * 16 + lrow;
#pragma unroll
      for (int ks = 0; ks < 2; ++ks) {
        const int s = (ks * 4 + quad) ^ (r & 7);
        af[fi][ks] = *(const bf16x8*)&sA[r * 64 + s * 8];
      }
    }
#pragma unroll
    for (int fj = 0; fj < 4; ++fj) {
      const int r = wn * 64 + fj * 16 + lrow;
#pragma unroll
      for (int ks = 0; ks < 2; ++ks) {
        const int s = (ks * 4 + quad) ^ (r & 7);
        bfr[fj][ks] = *(const bf16x8*)&sB[r * 64 + s * 8];
      }
    }
#pragma unroll
    for (int ks = 0; ks < 2; ++ks)
#pragma unroll
      for (int fi = 0; fi < 4; ++fi)
#pragma unroll
        for (int fj = 0; fj < 4; ++fj)
          acc[fi][fj] = __builtin_amdgcn_mfma_f32_16x16x32_bf16(af[fi][ks], bfr[fj][ks], acc[fi][fj], 0, 0, 0);
  }

  // epilogue: bias+activation -> bf16 -> sT (64 x 136 padded) -> coalesced stores
  const bool isZ = (bn < 2);
  ushort* gout = isZ ? zout : fout;
  const int ncol0 = (bn & 1) * 128;
  const float* bias = isZ ? bz : bfb;
  float bv[4];
#pragma unroll
  for (int fj = 0; fj < 4; ++fj)
    bv[fj] = bias[ncol0 + wn * 64 + fj * 16 + lrow];

  for (int round = 0; round < 2; ++round) {
    __syncthreads();
    if (wm == round) {
#pragma unroll
      for (int fi = 0; fi < 4; ++fi)
#pragma unroll
        for (int fj = 0; fj < 4; ++fj)
#pragma unroll
          for (int r = 0; r < 4; ++r) {
            float v = acc[fi][fj][r] + bv[fj];
            float o = isZ ? (v * sigf(1.702f * v)) : sigf(v);
            sT[(fi * 16 + quad * 4 + r) * 136 + wn * 64 + fj * 16 + lrow] = f2bf(o);
          }
    }
    __syncthreads();
#pragma unroll
    for (int it = 0; it < 4; ++it) {
      int e = tid + it * 256;           // 1024 segs = 64 rows x 16 segs
      int row = e >> 4, seg = e & 15;
      uint4 v = *(uint4*)&sT[row * 136 + seg * 8];
      *(uint4*)(gout + (size_t)(bm * 128 + round * 64 + row) * 256 + ncol0 + seg * 8) = v;
    }
  }
}

// ---- 3) per-chunk reduction, 2 channels/thread ----
__global__ void scanA_kernel(const ushort* __restrict__ z, const ushort* __restrict__ f,
                             float* __restrict__ Ac, float* __restrict__ Cc) {
  int t = blockIdx.x * blockDim.x + threadIdx.x;   // 0..131071
  int ch2 = t & 1023;
  int j = t >> 10;                                  // 0..127
  const size_t base = (size_t)j * CHUNK * NCH + 2 * ch2;
  const ushort* zp = z + base;
  const ushort* fp = f + base;
  float A0 = 1.0f, C0 = 0.0f, A1 = 1.0f, C1 = 0.0f;
#pragma unroll
  for (int i = 0; i < CHUNK; ++i) {
    ushort2 fv = *(const ushort2*)(fp + (size_t)i * NCH);
    ushort2 zv = *(const ushort2*)(zp + (size_t)i * NCH);
    float f0 = bf2f(fv.x), f1 = bf2f(fv.y);
    float a0 = 1.0f - f0, a1 = 1.0f - f1;
    C0 = fmaf(a0, C0, f0 * bf2f(zv.x)); A0 *= a0;
    C1 = fmaf(a1, C1, f1 * bf2f(zv.y)); A1 *= a1;
  }
  float2 Av = {A0, A1}, Cv = {C0, C1};
  *(float2*)(Ac + (size_t)j * NCH + 2 * ch2) = Av;
  *(float2*)(Cc + (size_t)j * NCH + 2 * ch2) = Cv;
}

// ---- 4) cross-chunk scan: one wave per channel, shfl Hillis-Steele ----
__global__ void scanB_kernel(const float* __restrict__ hidden,
                             const float* __restrict__ Ac, const float* __restrict__ Cc,
                             float* __restrict__ Hs) {
  const int lane = threadIdx.x & 63;
  const int ch = blockIdx.x * 4 + (threadIdx.x >> 6);   // 512 blocks x 4 waves
  const int j0 = 2 * lane, j1 = 2 * lane + 1;
  float a0 = Ac[j0 * NCH + ch], c0 = Cc[j0 * NCH + ch];
  float a1 = Ac[j1 * NCH + ch], c1 = Cc[j1 * NCH + ch];
  float a = a0 * a1;
  float c = fmaf(a1, c0, c1);
#pragma unroll
  for (int d = 1; d < 64; d <<= 1) {
    float pa = __shfl_up(a, d, 64);
    float pc = __shfl_up(c, d, 64);
    if (lane >= d) { c = fmaf(a, pc, c); a *= pa; }
  }
  float xa = __shfl_up(a, 1, 64), xc = __shfl_up(c, 1, 64);
  if (lane == 0) { xa = 1.0f; xc = 0.0f; }
  float h0 = hidden[ch];
  float hs0 = fmaf(xa, h0, xc);
  Hs[j0 * NCH + ch] = hs0;
  Hs[j1 * NCH + ch] = fmaf(a0, hs0, c0);
}

// ---- 5) replay within chunk, 2 channels/thread, fp32 out ----
__global__ void scanC_kernel(const ushort* __restrict__ z, const ushort* __restrict__ f,
                             const float* __restrict__ Hs, float* __restrict__ out) {
  int t = blockIdx.x * blockDim.x + threadIdx.x;   // 0..131071
  int ch2 = t & 1023;
  int j = t >> 10;
  float2 hv = *(const float2*)(Hs + (size_t)j * NCH + 2 * ch2);
  float h0 = hv.x, h1 = hv.y;
  const size_t base = (size_t)j * CHUNK * NCH + 2 * ch2;
  const ushort* zp = z + base;
  const ushort* fp = f + base;
  float* op = out + base;
#pragma unroll
  for (int i = 0; i < CHUNK; ++i) {
    ushort2 fv = *(const ushort2*)(fp + (size_t)i * NCH);
    ushort2 zv = *(const ushort2*)(zp + (size_t)i * NCH);
    float f0 = bf2f(fv.x), f1 = bf2f(fv.y);
    h0 = fmaf(f0, bf2f(zv.x) - h0, h0);
    h1 = fmaf(f1, bf2f(zv.y) - h1, h1);
    float2 o = {h0, h1};
    *(float2*)(op + (size_t)i * NCH) = o;
  }
  if (j == NCHUNK - 1) {
    float2 o = {h0, h1};
    *(float2*)(out + (size_t)SEQn * NCH + 2 * ch2) = o;   // h_last row
  }
}

extern "C" void kernel_launch(void* const* d_in, const int* in_sizes, int n_in,
                              void* d_out, int out_size, void* d_ws, size_t ws_size,
                              hipStream_t stream) {
  const float* X      = (const float*)d_in[0];
  const float* hidden = (const float*)d_in[1];
  const float* Wz     = (const float*)d_in[2];
  const float* bz     = (const float*)d_in[3];
  const float* Wf     = (const float*)d_in[4];
  const float* bfb    = (const float*)d_in[5];
  float* out = (float*)d_out;

  char* ws = (char*)d_ws;
  ushort* zbf = (ushort*)ws;                       // 16,777,216 B
  ushort* fbf = (ushort*)(ws + 16777216);          // 16,777,216 B
  float* Ac = (float*)(ws + 33554432);             // 1 MB
  float* Cc = (float*)(ws + 34603008);             // 1 MB
  float* Hs = (float*)(ws + 35651584);             // 1 MB
  ushort* Bm  = (ushort*)(ws + 36700160);          // 524,288 B

  pack_kernel<<<1024, 256, 0, stream>>>(Wz, Wf, Bm);
  dim3 ggrid(256, 4);
  gemm_kernel<<<ggrid, 256, 0, stream>>>(X, Bm, bz, bfb, zbf, fbf);
  scanA_kernel<<<512, 256, 0, stream>>>(zbf, fbf, Ac, Cc);
  scanB_kernel<<<512, 256, 0, stream>>>(hidden, Ac, Cc, Hs);
  scanC_kernel<<<512, 256, 0, stream>>>(zbf, fbf, Hs, out);
}

// Round 8
// 150.428 us; speedup vs baseline: 1.2396x; 1.0559x over previous
//
#include <hip/hip_runtime.h>

// QRNN: SEQ=4096, BATCH=8, CIN=256, HID=256, K=2 (lookback=1)
// R8: R3 structure + software-pipelined GEMM (BK=32, double-buffered LDS,
//     ONE barrier per K-iter, prefetch overlaps MFMA) + CHUNK=16 scans
//     (16 waves/CU). Act+bias in gemm epilogue (R3-proven).
//
// ws: zbf 16MB | fbf 16MB | Xbf 16MB (dead after gemm; Ac/Cc/Hs 6MB aliased) | Bm 0.5MB

#define SEQn 4096
#define NCH 2048          // BATCH*HID channels
#define CHUNK 16
#define NCHUNK 256

typedef __attribute__((ext_vector_type(8))) short bf16x8;
typedef __attribute__((ext_vector_type(4))) float floatx4;

__device__ __forceinline__ unsigned short f2bf(float x) {
  unsigned int u = __float_as_uint(x);
  u += 0x7fffu + ((u >> 16) & 1u);     // RNE
  return (unsigned short)(u >> 16);
}
__device__ __forceinline__ float bf2f(ushort u) {
  return __uint_as_float((unsigned int)u << 16);
}
__device__ __forceinline__ float sigf(float x) {
  return __builtin_amdgcn_rcpf(1.0f + __expf(-x));
}

// ---- 1) merged pack: blocks [0,1024) pack W, rest pack X (zero row in front) ----
__global__ void pack_kernel(const float* __restrict__ X,
                            const float* __restrict__ Wz, const float* __restrict__ Wf,
                            ushort* __restrict__ Xbf, ushort* __restrict__ Bm) {
  if (blockIdx.x < 1024) {
    int idx = blockIdx.x * 256 + threadIdx.x;        // 0..262143
    int n = idx >> 9, kin = idx & 511;
    const float* W = (n < 256) ? Wz : Wf;
    int h = n & 255, c = kin & 255, tap = kin >> 8;  // kin<256: tap0 (X[s-1])
    Bm[idx] = f2bf(W[h * 512 + c * 2 + tap]);
  } else {
    int idx = (blockIdx.x - 1024) * 256 + threadIdx.x;
    const int total4 = ((SEQn + 1) * NCH) / 4;       // 2,097,664
    if (idx >= total4) return;
    const int pad4 = NCH / 4;
    float4 v;
    if (idx < pad4) { v.x = 0.f; v.y = 0.f; v.z = 0.f; v.w = 0.f; }
    else v = ((const float4*)X)[idx - pad4];
    ushort4 o;
    o.x = f2bf(v.x); o.y = f2bf(v.y); o.z = f2bf(v.z); o.w = f2bf(v.w);
    ((ushort4*)Xbf)[idx] = o;
  }
}

// ---- 2) GEMM 128x128, BK=32, DOUBLE-BUFFERED LDS, one barrier/iter ----
// LDS: bufA at {0,16384}, bufB at {8192,24576}; slot (row,s) holds k-seg s^(row&3)
__global__ __launch_bounds__(256) void gemm_kernel(
    const ushort* __restrict__ Xbf, const ushort* __restrict__ Bm,
    const float* __restrict__ bz, const float* __restrict__ bfb,
    ushort* __restrict__ zout, ushort* __restrict__ fout) {
  __shared__ __align__(16) char smem_raw[32768];
  ushort* sT = (ushort*)smem_raw;                 // epilogue 64 x 136 (after last barrier)

  const int tid  = threadIdx.x;
  const int wave = tid >> 6;
  const int lane = tid & 63;
  const int quad = lane >> 4;
  const int lrow = lane & 15;
  const int wm = wave >> 1;          // 2x2 wave grid, 64x64 each
  const int wn = wave & 1;
  const int bm = blockIdx.x;         // 0..255
  const int bn = blockIdx.y;         // 0..3 (0,1=Z; 2,3=F)

  floatx4 acc[4][4];
#pragma unroll
  for (int i = 0; i < 4; ++i)
#pragma unroll
    for (int j = 0; j < 4; ++j)
      acc[i][j] = (floatx4){0.f, 0.f, 0.f, 0.f};

  // staging: 512 segs (128 rows x 4 k-segs of 8) per matrix; thread t -> segs t, t+256
  int rowS[2], gko[2];
#pragma unroll
  for (int it = 0; it < 2; ++it) {
    int g = it * 256 + wave * 64 + lane;
    int row = g >> 2, ks4 = g & 3;
    rowS[it] = row;
    gko[it] = (ks4 ^ (row & 3)) * 8;             // swizzled global k offset
  }
  char* ldsA = smem_raw + wave * 1024 + (lane << 4);          // + it*4096 + buf*16384
  char* ldsB = smem_raw + 8192 + wave * 1024 + (lane << 4);

  // prologue: stage k=0 into buf0
#pragma unroll
  for (int it = 0; it < 2; ++it) {
    const int kk = gko[it];                       // k0=0, always tap0 region
    __builtin_amdgcn_global_load_lds(
        (const __attribute__((address_space(1))) void*)(Xbf + (size_t)(bm * 128 + rowS[it]) * 256 + kk),
        (__attribute__((address_space(3))) void*)(ldsA + it * 4096), 16, 0, 0);
    __builtin_amdgcn_global_load_lds(
        (const __attribute__((address_space(1))) void*)(Bm + (size_t)(bn * 128 + rowS[it]) * 512 + kk),
        (__attribute__((address_space(3))) void*)(ldsB + it * 4096), 16, 0, 0);
  }
  __syncthreads();

#pragma unroll
  for (int k = 0; k < 16; ++k) {                  // K=512, BK=32
    const int cur = k & 1;
    const int bo = cur * 16384;

    // frag reads from buf[cur] (issued first; lgkm wait lands before MFMA use)
    bf16x8 af[4], bfr[4];
#pragma unroll
    for (int fi = 0; fi < 4; ++fi) {
      const int r = wm * 64 + fi * 16 + lrow;
      const int s = quad ^ (r & 3);
      af[fi] = *(const bf16x8*)(smem_raw + bo + r * 64 + s * 16);
    }
#pragma unroll
    for (int fj = 0; fj < 4; ++fj) {
      const int r = wn * 64 + fj * 16 + lrow;
      const int s = quad ^ (r & 3);
      bfr[fj] = *(const bf16x8*)(smem_raw + bo + 8192 + r * 64 + s * 16);
    }

    // prefetch k+1 into buf[cur^1] (async; drained by end-of-iter barrier)
    if (k < 15) {
      const int nbo = (cur ^ 1) * 16384;
      const int k0 = (k + 1) * 32;
#pragma unroll
      for (int it = 0; it < 2; ++it) {
        const int kk = k0 + gko[it];
        const int cA = (kk < 256) ? kk : kk + 1792;   // tap1 lives +2048-256
        __builtin_amdgcn_global_load_lds(
            (const __attribute__((address_space(1))) void*)(Xbf + (size_t)(bm * 128 + rowS[it]) * 256 + cA),
            (__attribute__((address_space(3))) void*)(ldsA + nbo + it * 4096), 16, 0, 0);
        __builtin_amdgcn_global_load_lds(
            (const __attribute__((address_space(1))) void*)(Bm + (size_t)(bn * 128 + rowS[it]) * 512 + kk),
            (__attribute__((address_space(3))) void*)(ldsB + nbo + it * 4096), 16, 0, 0);
      }
    }

#pragma unroll
    for (int fi = 0; fi < 4; ++fi)
#pragma unroll
      for (int fj = 0; fj < 4; ++fj)
        acc[fi][fj] = __builtin_amdgcn_mfma_f32_16x16x32_bf16(af[fi], bfr[fj], acc[fi][fj], 0, 0, 0);

    __syncthreads();                  // drains ds reads + prefetch vmcnt
  }

  // epilogue: bias+activation -> bf16 -> sT (64 x 136 padded) -> coalesced stores
  const bool isZ = (bn < 2);
  ushort* gout = isZ ? zout : fout;
  const int ncol0 = (bn & 1) * 128;
  const float* bias = isZ ? bz : bfb;
  float bv[4];
#pragma unroll
  for (int fj = 0; fj < 4; ++fj)
    bv[fj] = bias[ncol0 + wn * 64 + fj * 16 + lrow];

  for (int round = 0; round < 2; ++round) {
    __syncthreads();
    if (wm == round) {
#pragma unroll
      for (int fi = 0; fi < 4; ++fi)
#pragma unroll
        for (int fj = 0; fj < 4; ++fj)
#pragma unroll
          for (int r = 0; r < 4; ++r) {
            float v = acc[fi][fj][r] + bv[fj];
            float o = isZ ? (v * sigf(1.702f * v)) : sigf(v);
            sT[(fi * 16 + quad * 4 + r) * 136 + wn * 64 + fj * 16 + lrow] = f2bf(o);
          }
    }
    __syncthreads();
#pragma unroll
    for (int it = 0; it < 4; ++it) {
      int e = tid + it * 256;           // 1024 segs = 64 rows x 16 segs
      int row = e >> 4, seg = e & 15;
      uint4 v = *(uint4*)&sT[row * 136 + seg * 8];
      *(uint4*)(gout + (size_t)(bm * 128 + round * 64 + row) * 256 + ncol0 + seg * 8) = v;
    }
  }
}

// ---- 3) per-chunk (16-step) reduction, 2 channels/thread ----
__global__ void scanA_kernel(const ushort* __restrict__ z, const ushort* __restrict__ f,
                             float* __restrict__ Ac, float* __restrict__ Cc) {
  int t = blockIdx.x * blockDim.x + threadIdx.x;   // 0..262143
  int ch2 = t & 1023;
  int j = t >> 10;                                  // 0..255
  const size_t base = (size_t)j * CHUNK * NCH + 2 * ch2;
  const ushort* zp = z + base;
  const ushort* fp = f + base;
  float A0 = 1.0f, C0 = 0.0f, A1 = 1.0f, C1 = 0.0f;
#pragma unroll
  for (int i = 0; i < CHUNK; ++i) {
    ushort2 fv = *(const ushort2*)(fp + (size_t)i * NCH);
    ushort2 zv = *(const ushort2*)(zp + (size_t)i * NCH);
    float f0 = bf2f(fv.x), f1 = bf2f(fv.y);
    float a0 = 1.0f - f0, a1 = 1.0f - f1;
    C0 = fmaf(a0, C0, f0 * bf2f(zv.x)); A0 *= a0;
    C1 = fmaf(a1, C1, f1 * bf2f(zv.y)); A1 *= a1;
  }
  float2 Av = {A0, A1}, Cv = {C0, C1};
  *(float2*)(Ac + (size_t)j * NCH + 2 * ch2) = Av;
  *(float2*)(Cc + (size_t)j * NCH + 2 * ch2) = Cv;
}

// ---- 4) cross-chunk scan: one wave/channel, 4 chunks/lane, shfl Hillis-Steele ----
__global__ void scanB_kernel(const float* __restrict__ hidden,
                             const float* __restrict__ Ac, const float* __restrict__ Cc,
                             float* __restrict__ Hs) {
  const int lane = threadIdx.x & 63;
  const int ch = blockIdx.x * 4 + (threadIdx.x >> 6);   // 512 blocks x 4 waves
  float al[4], cl[4];
#pragma unroll
  for (int i = 0; i < 4; ++i) {
    al[i] = Ac[(size_t)(4 * lane + i) * NCH + ch];
    cl[i] = Cc[(size_t)(4 * lane + i) * NCH + ch];
  }
  // compose lane's 4 chunks (later ∘ earlier)
  float a = al[0], c = cl[0];
#pragma unroll
  for (int i = 1; i < 4; ++i) { c = fmaf(al[i], c, cl[i]); a *= al[i]; }
#pragma unroll
  for (int d = 1; d < 64; d <<= 1) {
    float pa = __shfl_up(a, d, 64);
    float pc = __shfl_up(c, d, 64);
    if (lane >= d) { c = fmaf(a, pc, c); a *= pa; }
  }
  float xa = __shfl_up(a, 1, 64), xc = __shfl_up(c, 1, 64);
  if (lane == 0) { xa = 1.0f; xc = 0.0f; }
  float h = fmaf(xa, hidden[ch], xc);             // h at start of chunk 4*lane
#pragma unroll
  for (int i = 0; i < 4; ++i) {
    Hs[(size_t)(4 * lane + i) * NCH + ch] = h;
    h = fmaf(al[i], h, cl[i]);
  }
}

// ---- 5) replay within chunk, 2 channels/thread, fp32 out ----
__global__ void scanC_kernel(const ushort* __restrict__ z, const ushort* __restrict__ f,
                             const float* __restrict__ Hs, float* __restrict__ out) {
  int t = blockIdx.x * blockDim.x + threadIdx.x;   // 0..262143
  int ch2 = t & 1023;
  int j = t >> 10;
  float2 hv = *(const float2*)(Hs + (size_t)j * NCH + 2 * ch2);
  float h0 = hv.x, h1 = hv.y;
  const size_t base = (size_t)j * CHUNK * NCH + 2 * ch2;
  const ushort* zp = z + base;
  const ushort* fp = f + base;
  float* op = out + base;
#pragma unroll
  for (int i = 0; i < CHUNK; ++i) {
    ushort2 fv = *(const ushort2*)(fp + (size_t)i * NCH);
    ushort2 zv = *(const ushort2*)(zp + (size_t)i * NCH);
    float f0 = bf2f(fv.x), f1 = bf2f(fv.y);
    h0 = fmaf(f0, bf2f(zv.x) - h0, h0);
    h1 = fmaf(f1, bf2f(zv.y) - h1, h1);
    float2 o = {h0, h1};
    *(float2*)(op + (size_t)i * NCH) = o;
  }
  if (j == NCHUNK - 1) {
    float2 o = {h0, h1};
    *(float2*)(out + (size_t)SEQn * NCH + 2 * ch2) = o;   // h_last row
  }
}

extern "C" void kernel_launch(void* const* d_in, const int* in_sizes, int n_in,
                              void* d_out, int out_size, void* d_ws, size_t ws_size,
                              hipStream_t stream) {
  const float* X      = (const float*)d_in[0];
  const float* hidden = (const float*)d_in[1];
  const float* Wz     = (const float*)d_in[2];
  const float* bz     = (const float*)d_in[3];
  const float* Wf     = (const float*)d_in[4];
  const float* bfb    = (const float*)d_in[5];
  float* out = (float*)d_out;

  char* ws = (char*)d_ws;
  ushort* zbf = (ushort*)ws;                       // 16,777,216 B
  ushort* fbf = (ushort*)(ws + 16777216);          // 16,777,216 B
  ushort* Xbf = (ushort*)(ws + 33554432);          // 16,781,312 B (dead after gemm)
  ushort* Bm  = (ushort*)(ws + 50335744);          //    524,288 B
  // aliased over Xbf (used only after gemm completes):
  float* Ac = (float*)(ws + 33554432);             // 2 MB
  float* Cc = (float*)(ws + 35651584);             // 2 MB
  float* Hs = (float*)(ws + 37748736);             // 2 MB

  pack_kernel<<<9218, 256, 0, stream>>>(X, Wz, Wf, Xbf, Bm);
  dim3 ggrid(256, 4);
  gemm_kernel<<<ggrid, 256, 0, stream>>>(Xbf, Bm, bz, bfb, zbf, fbf);
  scanA_kernel<<<1024, 256, 0, stream>>>(zbf, fbf, Ac, Cc);
  scanB_kernel<<<512, 256, 0, stream>>>(hidden, Ac, Cc, Hs);
  scanC_kernel<<<1024, 256, 0, stream>>>(zbf, fbf, Hs, out);
}